// Round 1
// baseline (139.690 us; speedup 1.0000x reference)
//
#include <hip/hip_runtime.h>

#define NUM_BINS  512
#define NUM_NODES 128
#define K_ELEMS   16384
#define N_PAIRS   1024

// ---------------------------------------------------------------------------
// Pass 0: zero the workspace (hist + tw). Kernel (not hipMemsetAsync) to be
// maximally graph-capture-safe.
// ---------------------------------------------------------------------------
__global__ __launch_bounds__(256) void zero_ws_kernel(float* __restrict__ ws, int n)
{
    int i = blockIdx.x * 256 + threadIdx.x;
    if (i < n) ws[i] = 0.0f;
}

// ---------------------------------------------------------------------------
// Pass 1: per-row LDS histogram + weight total, flushed to hist[src], hist[dst]
// and tw[src], tw[dst]. One block per row.
// ---------------------------------------------------------------------------
__global__ __launch_bounds__(256) void hist_kernel(
    const float* __restrict__ residuals, const float* __restrict__ weights,
    const int* __restrict__ src, const int* __restrict__ dst,
    float* __restrict__ hist, float* __restrict__ tw)
{
    __shared__ float lhist[NUM_BINS];
    __shared__ float swsum[4];
    const int row = blockIdx.x;
    const int t   = threadIdx.x;

    for (int i = t; i < NUM_BINS; i += 256) lhist[i] = 0.0f;
    __syncthreads();

    const float4* r4 = (const float4*)(residuals + (size_t)row * K_ELEMS);
    const float4* w4 = (const float4*)(weights   + (size_t)row * K_ELEMS);

    float wsum = 0.0f;
    // K_ELEMS/4 = 4096 float4 per row; 256 threads -> 16 iters
    for (int i = t; i < K_ELEMS / 4; i += 256) {
        float4 r = r4[i];
        float4 w = w4[i];
        wsum += w.x + w.y + w.z + w.w;   // tw is the UNMASKED weight sum
        int b;
        b = (int)floorf(r.x * 512.0f); if (b >= 0 && b < NUM_BINS) atomicAdd(&lhist[b], w.x);
        b = (int)floorf(r.y * 512.0f); if (b >= 0 && b < NUM_BINS) atomicAdd(&lhist[b], w.y);
        b = (int)floorf(r.z * 512.0f); if (b >= 0 && b < NUM_BINS) atomicAdd(&lhist[b], w.z);
        b = (int)floorf(r.w * 512.0f); if (b >= 0 && b < NUM_BINS) atomicAdd(&lhist[b], w.w);
    }

    // block-reduce wsum: wave64 shuffle then LDS
    for (int off = 32; off > 0; off >>= 1) wsum += __shfl_down(wsum, off, 64);
    const int wave = t >> 6, lane = t & 63;
    if (lane == 0) swsum[wave] = wsum;
    __syncthreads();

    const int s = src[row], d = dst[row];
    if (t == 0) {
        float tot = swsum[0] + swsum[1] + swsum[2] + swsum[3];
        atomicAdd(&tw[s], tot);
        atomicAdd(&tw[d], tot);   // added to BOTH even if s == d (matches ref)
    }

    // flush local histogram to both node rows
    for (int i = t; i < NUM_BINS; i += 256) {
        float v = lhist[i];
        if (v != 0.0f) {
            atomicAdd(&hist[s * NUM_BINS + i], v);
            atomicAdd(&hist[d * NUM_BINS + i], v);
        }
    }
}

// ---------------------------------------------------------------------------
// Pass 2: pmf = hist / (tw + 1e-10); cdf = inclusive scan. In-place on hist.
// One block (512 threads) per node. Hillis-Steele scan in LDS.
// ---------------------------------------------------------------------------
__global__ __launch_bounds__(512) void scan_kernel(float* __restrict__ hist,
                                                   const float* __restrict__ tw)
{
    __shared__ float s[NUM_BINS];
    const int node = blockIdx.x;
    const int t    = threadIdx.x;

    const float denom = tw[node] + 1e-10f;
    s[t] = hist[node * NUM_BINS + t] / denom;
    __syncthreads();

    for (int off = 1; off < NUM_BINS; off <<= 1) {
        float add = (t >= off) ? s[t - off] : 0.0f;
        __syncthreads();
        s[t] += add;
        __syncthreads();
    }
    hist[node * NUM_BINS + t] = s[t];
}

// ---------------------------------------------------------------------------
// Pass 3: lookup. 4 blocks per row; cdf rows for src/dst staged in LDS.
// ---------------------------------------------------------------------------
__global__ __launch_bounds__(256) void lookup_kernel(
    const float* __restrict__ residuals, const float* __restrict__ weights,
    const int* __restrict__ src, const int* __restrict__ dst,
    const float* __restrict__ cdf,
    float* __restrict__ out_src, float* __restrict__ out_dst)
{
    __shared__ float scdf[NUM_BINS];
    __shared__ float dcdf[NUM_BINS];
    const int CHUNK = K_ELEMS / 4;          // 4096 elements per block
    const int row   = blockIdx.x >> 2;
    const int chunk = blockIdx.x & 3;
    const int t     = threadIdx.x;

    const int s = src[row], d = dst[row];
    for (int i = t; i < NUM_BINS; i += 256) {
        scdf[i] = cdf[s * NUM_BINS + i];
        dcdf[i] = cdf[d * NUM_BINS + i];
    }
    __syncthreads();

    const size_t base = (size_t)row * K_ELEMS + (size_t)chunk * CHUNK;
    const float4* r4  = (const float4*)(residuals + base);
    const float4* w4  = (const float4*)(weights   + base);
    float4*       os4 = (float4*)(out_src + base);
    float4*       od4 = (float4*)(out_dst + base);

    for (int i = t; i < CHUNK / 4; i += 256) {   // 4 iters
        float4 r = r4[i], w = w4[i];
        float4 osv, odv;

        {   int b = (int)floorf(r.x * 512.0f + 0.5f);
            bool valid = (b >= 0) & (b < NUM_BINS) & (w.x > 0.0f);
            int bc = min(max(b, 0), NUM_BINS - 1);
            osv.x = valid ? scdf[bc] : 2.0f;
            odv.x = valid ? dcdf[bc] : 2.0f; }
        {   int b = (int)floorf(r.y * 512.0f + 0.5f);
            bool valid = (b >= 0) & (b < NUM_BINS) & (w.y > 0.0f);
            int bc = min(max(b, 0), NUM_BINS - 1);
            osv.y = valid ? scdf[bc] : 2.0f;
            odv.y = valid ? dcdf[bc] : 2.0f; }
        {   int b = (int)floorf(r.z * 512.0f + 0.5f);
            bool valid = (b >= 0) & (b < NUM_BINS) & (w.z > 0.0f);
            int bc = min(max(b, 0), NUM_BINS - 1);
            osv.z = valid ? scdf[bc] : 2.0f;
            odv.z = valid ? dcdf[bc] : 2.0f; }
        {   int b = (int)floorf(r.w * 512.0f + 0.5f);
            bool valid = (b >= 0) & (b < NUM_BINS) & (w.w > 0.0f);
            int bc = min(max(b, 0), NUM_BINS - 1);
            osv.w = valid ? scdf[bc] : 2.0f;
            odv.w = valid ? dcdf[bc] : 2.0f; }

        os4[i] = osv;
        od4[i] = odv;
    }
}

// ---------------------------------------------------------------------------
extern "C" void kernel_launch(void* const* d_in, const int* in_sizes, int n_in,
                              void* d_out, int out_size, void* d_ws, size_t ws_size,
                              hipStream_t stream)
{
    const float* residuals = (const float*)d_in[0];
    const float* weights   = (const float*)d_in[1];
    const int*   src       = (const int*)d_in[2];
    const int*   dst       = (const int*)d_in[3];

    float* out_src = (float*)d_out;
    float* out_dst = out_src + (size_t)N_PAIRS * K_ELEMS;

    float* hist = (float*)d_ws;                    // 128*512 floats
    float* tw   = hist + NUM_NODES * NUM_BINS;     // 128 floats

    const int ws_elems = NUM_NODES * NUM_BINS + NUM_NODES;
    zero_ws_kernel<<<(ws_elems + 255) / 256, 256, 0, stream>>>((float*)d_ws, ws_elems);

    hist_kernel<<<N_PAIRS, 256, 0, stream>>>(residuals, weights, src, dst, hist, tw);

    scan_kernel<<<NUM_NODES, NUM_BINS, 0, stream>>>(hist, tw);

    lookup_kernel<<<N_PAIRS * 4, 256, 0, stream>>>(residuals, weights, src, dst,
                                                   hist, out_src, out_dst);
}

// Round 2
// 139.482 us; speedup vs baseline: 1.0015x; 1.0015x over previous
//
#include <hip/hip_runtime.h>

#define NUM_BINS  512
#define NUM_NODES 128
#define K_ELEMS   16384
#define N_PAIRS   1024

// Native FP32 atomic add (ds_add_f32 / global_atomic_add_f32) — avoids the
// CAS-loop that plain atomicAdd(float*) compiles to without unsafe-fp-atomics.
__device__ __forceinline__ void fadd(float* p, float v) { unsafeAtomicAdd(p, v); }

// ---------------------------------------------------------------------------
// Pass 0: zero the workspace (hist + tw).
// ---------------------------------------------------------------------------
__global__ __launch_bounds__(256) void zero_ws_kernel(float* __restrict__ ws, int n)
{
    int i = blockIdx.x * 256 + threadIdx.x;
    if (i < n) ws[i] = 0.0f;
}

// ---------------------------------------------------------------------------
// Pass 1: per-row LDS histogram + weight total, flushed to hist[src], hist[dst]
// and tw[src], tw[dst]. One block (512 thr = 8 waves) per row.
// ---------------------------------------------------------------------------
__global__ __launch_bounds__(512) void hist_kernel(
    const float* __restrict__ residuals, const float* __restrict__ weights,
    const int* __restrict__ src, const int* __restrict__ dst,
    float* __restrict__ hist, float* __restrict__ tw)
{
    __shared__ float lhist[NUM_BINS];
    __shared__ float swsum[8];
    const int row = blockIdx.x;
    const int t   = threadIdx.x;

    if (t < NUM_BINS) lhist[t] = 0.0f;
    __syncthreads();

    const float4* r4 = (const float4*)(residuals + (size_t)row * K_ELEMS);
    const float4* w4 = (const float4*)(weights   + (size_t)row * K_ELEMS);

    float wsum = 0.0f;
    // K_ELEMS/4 = 4096 float4 per row; 512 threads -> 8 iters
    for (int i = t; i < K_ELEMS / 4; i += 512) {
        float4 r = r4[i];
        float4 w = w4[i];
        wsum += w.x + w.y + w.z + w.w;   // tw is the UNMASKED weight sum
        int b;
        b = (int)floorf(r.x * 512.0f); if ((unsigned)b < (unsigned)NUM_BINS) fadd(&lhist[b], w.x);
        b = (int)floorf(r.y * 512.0f); if ((unsigned)b < (unsigned)NUM_BINS) fadd(&lhist[b], w.y);
        b = (int)floorf(r.z * 512.0f); if ((unsigned)b < (unsigned)NUM_BINS) fadd(&lhist[b], w.z);
        b = (int)floorf(r.w * 512.0f); if ((unsigned)b < (unsigned)NUM_BINS) fadd(&lhist[b], w.w);
    }

    // block-reduce wsum: wave64 shuffle then LDS
    for (int off = 32; off > 0; off >>= 1) wsum += __shfl_down(wsum, off, 64);
    const int wave = t >> 6, lane = t & 63;
    if (lane == 0) swsum[wave] = wsum;
    __syncthreads();

    const int s = src[row], d = dst[row];
    if (t == 0) {
        float tot = 0.0f;
        #pragma unroll
        for (int i = 0; i < 8; ++i) tot += swsum[i];
        fadd(&tw[s], tot);
        fadd(&tw[d], tot);   // added to BOTH even if s == d (matches ref)
    }

    // flush local histogram to both node rows
    if (t < NUM_BINS) {
        float v = lhist[t];
        if (v != 0.0f) {
            fadd(&hist[s * NUM_BINS + t], v);
            fadd(&hist[d * NUM_BINS + t], v);
        }
    }
}

// ---------------------------------------------------------------------------
// Pass 2: pmf = hist / (tw + 1e-10); cdf = inclusive scan. In-place on hist.
// One block (512 threads) per node. Hillis-Steele scan in LDS.
// ---------------------------------------------------------------------------
__global__ __launch_bounds__(512) void scan_kernel(float* __restrict__ hist,
                                                   const float* __restrict__ tw)
{
    __shared__ float s[NUM_BINS];
    const int node = blockIdx.x;
    const int t    = threadIdx.x;

    const float denom = tw[node] + 1e-10f;
    s[t] = hist[node * NUM_BINS + t] / denom;
    __syncthreads();

    for (int off = 1; off < NUM_BINS; off <<= 1) {
        float add = (t >= off) ? s[t - off] : 0.0f;
        __syncthreads();
        s[t] += add;
        __syncthreads();
    }
    hist[node * NUM_BINS + t] = s[t];
}

// ---------------------------------------------------------------------------
// Pass 3: lookup. 4 blocks per row; cdf rows for src/dst staged in LDS.
// ---------------------------------------------------------------------------
__global__ __launch_bounds__(256) void lookup_kernel(
    const float* __restrict__ residuals, const float* __restrict__ weights,
    const int* __restrict__ src, const int* __restrict__ dst,
    const float* __restrict__ cdf,
    float* __restrict__ out_src, float* __restrict__ out_dst)
{
    __shared__ float scdf[NUM_BINS];
    __shared__ float dcdf[NUM_BINS];
    const int CHUNK = K_ELEMS / 4;          // 4096 elements per block
    const int row   = blockIdx.x >> 2;
    const int chunk = blockIdx.x & 3;
    const int t     = threadIdx.x;

    const int s = src[row], d = dst[row];
    for (int i = t; i < NUM_BINS; i += 256) {
        scdf[i] = cdf[s * NUM_BINS + i];
        dcdf[i] = cdf[d * NUM_BINS + i];
    }
    __syncthreads();

    const size_t base = (size_t)row * K_ELEMS + (size_t)chunk * CHUNK;
    const float4* r4  = (const float4*)(residuals + base);
    const float4* w4  = (const float4*)(weights   + base);
    float4*       os4 = (float4*)(out_src + base);
    float4*       od4 = (float4*)(out_dst + base);

    for (int i = t; i < CHUNK / 4; i += 256) {   // 4 iters
        float4 r = r4[i], w = w4[i];
        float4 osv, odv;

        {   int b = (int)floorf(r.x * 512.0f + 0.5f);
            bool valid = (b >= 0) & (b < NUM_BINS) & (w.x > 0.0f);
            int bc = min(max(b, 0), NUM_BINS - 1);
            osv.x = valid ? scdf[bc] : 2.0f;
            odv.x = valid ? dcdf[bc] : 2.0f; }
        {   int b = (int)floorf(r.y * 512.0f + 0.5f);
            bool valid = (b >= 0) & (b < NUM_BINS) & (w.y > 0.0f);
            int bc = min(max(b, 0), NUM_BINS - 1);
            osv.y = valid ? scdf[bc] : 2.0f;
            odv.y = valid ? dcdf[bc] : 2.0f; }
        {   int b = (int)floorf(r.z * 512.0f + 0.5f);
            bool valid = (b >= 0) & (b < NUM_BINS) & (w.z > 0.0f);
            int bc = min(max(b, 0), NUM_BINS - 1);
            osv.z = valid ? scdf[bc] : 2.0f;
            odv.z = valid ? dcdf[bc] : 2.0f; }
        {   int b = (int)floorf(r.w * 512.0f + 0.5f);
            bool valid = (b >= 0) & (b < NUM_BINS) & (w.w > 0.0f);
            int bc = min(max(b, 0), NUM_BINS - 1);
            osv.w = valid ? scdf[bc] : 2.0f;
            odv.w = valid ? dcdf[bc] : 2.0f; }

        os4[i] = osv;
        od4[i] = odv;
    }
}

// ---------------------------------------------------------------------------
extern "C" void kernel_launch(void* const* d_in, const int* in_sizes, int n_in,
                              void* d_out, int out_size, void* d_ws, size_t ws_size,
                              hipStream_t stream)
{
    const float* residuals = (const float*)d_in[0];
    const float* weights   = (const float*)d_in[1];
    const int*   src       = (const int*)d_in[2];
    const int*   dst       = (const int*)d_in[3];

    float* out_src = (float*)d_out;
    float* out_dst = out_src + (size_t)N_PAIRS * K_ELEMS;

    float* hist = (float*)d_ws;                    // 128*512 floats
    float* tw   = hist + NUM_NODES * NUM_BINS;     // 128 floats

    const int ws_elems = NUM_NODES * NUM_BINS + NUM_NODES;
    zero_ws_kernel<<<(ws_elems + 255) / 256, 256, 0, stream>>>((float*)d_ws, ws_elems);

    hist_kernel<<<N_PAIRS, 512, 0, stream>>>(residuals, weights, src, dst, hist, tw);

    scan_kernel<<<NUM_NODES, NUM_BINS, 0, stream>>>(hist, tw);

    lookup_kernel<<<N_PAIRS * 4, 256, 0, stream>>>(residuals, weights, src, dst,
                                                   hist, out_src, out_dst);
}

// Round 3
// 114.170 us; speedup vs baseline: 1.2235x; 1.2217x over previous
//
#include <hip/hip_runtime.h>

#define NUM_BINS  512
#define NUM_NODES 128
#define K_ELEMS   16384
#define N_PAIRS   1024
#define NCOPY     32

__device__ __forceinline__ void fadd(float* p, float v) { unsafeAtomicAdd(p, v); }

// ---------------------------------------------------------------------------
// Pass 0: zero the workspace (hist + tw).
// ---------------------------------------------------------------------------
__global__ __launch_bounds__(256) void zero_ws_kernel(float* __restrict__ ws, int n)
{
    int i = blockIdx.x * 256 + threadIdx.x;
    if (i < n) ws[i] = 0.0f;
}

// ---------------------------------------------------------------------------
// Pass 1: per-row histogram WITHOUT LDS atomics.
// 1 wave per row. 32 LDS histogram copies (64 KB), copy = lane & 31, so each
// copy is touched only by the lane pair (l, l+32). Races are resolved by
// making every write to a given (bin,copy) address carry the IDENTICAL value:
//   val = lds_read(bin) + sum of raw weights of ALL slots (both lanes of the
//         pair, all 4 float4 components) whose bin matches.
// Duplicate writes are then benign. Bank index = lane&31 -> 2-way (free).
// ---------------------------------------------------------------------------
__global__ __launch_bounds__(64) void hist_kernel(
    const float* __restrict__ residuals, const float* __restrict__ weights,
    const int* __restrict__ src, const int* __restrict__ dst,
    float* __restrict__ hist, float* __restrict__ tw)
{
    __shared__ float lh[NUM_BINS * NCOPY];     // 65536 bytes exactly
    const int row  = blockIdx.x;
    const int l    = threadIdx.x;              // 0..63
    const int copy = l & 31;

    // zero 16384 floats with b128 stores
    float4* lh4 = (float4*)lh;
    #pragma unroll
    for (int k = 0; k < NUM_BINS * NCOPY / 4 / 64; ++k) {
        float4 z; z.x = z.y = z.z = z.w = 0.0f;
        lh4[l + k * 64] = z;
    }
    __syncthreads();

    const float4* r4 = (const float4*)(residuals + (size_t)row * K_ELEMS);
    const float4* w4 = (const float4*)(weights   + (size_t)row * K_ELEMS);

    float wsum = 0.0f;
    // 4096 float4 per row / 64 lanes = 64 iterations
    #pragma unroll 4
    for (int it = 0; it < K_ELEMS / 4 / 64; ++it) {
        float4 r = r4[l + it * 64];
        float4 w = w4[l + it * 64];
        wsum += w.x + w.y + w.z + w.w;          // tw is UNMASKED sum

        int   b0, b1, b2, b3;
        float v0, v1, v2, v3;
        b0 = (int)floorf(r.x * 512.0f); v0 = ((unsigned)b0 < 512u) ? w.x : 0.0f; b0 = ((unsigned)b0 < 512u) ? b0 : 0;
        b1 = (int)floorf(r.y * 512.0f); v1 = ((unsigned)b1 < 512u) ? w.y : 0.0f; b1 = ((unsigned)b1 < 512u) ? b1 : 0;
        b2 = (int)floorf(r.z * 512.0f); v2 = ((unsigned)b2 < 512u) ? w.z : 0.0f; b2 = ((unsigned)b2 < 512u) ? b2 : 0;
        b3 = (int)floorf(r.w * 512.0f); v3 = ((unsigned)b3 < 512u) ? w.w : 0.0f; b3 = ((unsigned)b3 < 512u) ? b3 : 0;

        // partner (lane ^ 32) raw slots
        int   q0 = __shfl_xor(b0, 32), q1 = __shfl_xor(b1, 32),
              q2 = __shfl_xor(b2, 32), q3 = __shfl_xor(b3, 32);
        float u0 = __shfl_xor(v0, 32), u1 = __shfl_xor(v1, 32),
              u2 = __shfl_xor(v2, 32), u3 = __shfl_xor(v3, 32);

        // symmetric per-slot totals over all 8 slots of the pair
        float a0 = v0 + (b1 == b0 ? v1 : 0.0f) + (b2 == b0 ? v2 : 0.0f) + (b3 == b0 ? v3 : 0.0f)
                      + (q0 == b0 ? u0 : 0.0f) + (q1 == b0 ? u1 : 0.0f) + (q2 == b0 ? u2 : 0.0f) + (q3 == b0 ? u3 : 0.0f);
        float a1 = v1 + (b0 == b1 ? v0 : 0.0f) + (b2 == b1 ? v2 : 0.0f) + (b3 == b1 ? v3 : 0.0f)
                      + (q0 == b1 ? u0 : 0.0f) + (q1 == b1 ? u1 : 0.0f) + (q2 == b1 ? u2 : 0.0f) + (q3 == b1 ? u3 : 0.0f);
        float a2 = v2 + (b0 == b2 ? v0 : 0.0f) + (b1 == b2 ? v1 : 0.0f) + (b3 == b2 ? v3 : 0.0f)
                      + (q0 == b2 ? u0 : 0.0f) + (q1 == b2 ? u1 : 0.0f) + (q2 == b2 ? u2 : 0.0f) + (q3 == b2 ? u3 : 0.0f);
        float a3 = v3 + (b0 == b3 ? v0 : 0.0f) + (b1 == b3 ? v1 : 0.0f) + (b2 == b3 ? v2 : 0.0f)
                      + (q0 == b3 ? u0 : 0.0f) + (q1 == b3 ? u1 : 0.0f) + (q2 == b3 ? u2 : 0.0f) + (q3 == b3 ? u3 : 0.0f);

        // non-atomic RMW: reads independent; same-address writes carry equal values
        const int i0 = b0 * NCOPY + copy, i1 = b1 * NCOPY + copy,
                  i2 = b2 * NCOPY + copy, i3 = b3 * NCOPY + copy;
        float h0 = lh[i0], h1 = lh[i1], h2 = lh[i2], h3 = lh[i3];
        lh[i0] = h0 + a0;
        lh[i1] = h1 + a1;
        lh[i2] = h2 + a2;
        lh[i3] = h3 + a3;
    }

    __syncthreads();   // drain LDS before the copy-reduction

    // wave-wide weight total (butterfly)
    #pragma unroll
    for (int off = 32; off > 0; off >>= 1) wsum += __shfl_xor(wsum, off);

    const int s = src[row], d = dst[row];
    if (l == 0) {
        fadd(&tw[s], wsum);
        fadd(&tw[d], wsum);   // both, even if s == d (matches ref)
    }

    // reduce the 32 copies; lane handles bins l, l+64, ... (rotated copy index
    // -> bank = (l+cc)&31, lanes l and l+32 share a bank: 2-way, free)
    #pragma unroll
    for (int j = 0; j < NUM_BINS / 64; ++j) {
        const int bin = l + j * 64;
        float tot = 0.0f;
        #pragma unroll
        for (int cc = 0; cc < NCOPY; ++cc)
            tot += lh[bin * NCOPY + ((l + cc) & 31)];
        fadd(&hist[s * NUM_BINS + bin], tot);
        fadd(&hist[d * NUM_BINS + bin], tot);
    }
}

// ---------------------------------------------------------------------------
// Pass 2: pmf = hist / (tw + 1e-10); cdf = inclusive scan. In-place on hist.
// ---------------------------------------------------------------------------
__global__ __launch_bounds__(512) void scan_kernel(float* __restrict__ hist,
                                                   const float* __restrict__ tw)
{
    __shared__ float s[NUM_BINS];
    const int node = blockIdx.x;
    const int t    = threadIdx.x;

    const float denom = tw[node] + 1e-10f;
    s[t] = hist[node * NUM_BINS + t] / denom;
    __syncthreads();

    for (int off = 1; off < NUM_BINS; off <<= 1) {
        float add = (t >= off) ? s[t - off] : 0.0f;
        __syncthreads();
        s[t] += add;
        __syncthreads();
    }
    hist[node * NUM_BINS + t] = s[t];
}

// ---------------------------------------------------------------------------
// Pass 3: lookup. 4 blocks per row; cdf rows for src/dst staged in LDS.
// ---------------------------------------------------------------------------
__global__ __launch_bounds__(256) void lookup_kernel(
    const float* __restrict__ residuals, const float* __restrict__ weights,
    const int* __restrict__ src, const int* __restrict__ dst,
    const float* __restrict__ cdf,
    float* __restrict__ out_src, float* __restrict__ out_dst)
{
    __shared__ float scdf[NUM_BINS];
    __shared__ float dcdf[NUM_BINS];
    const int CHUNK = K_ELEMS / 4;
    const int row   = blockIdx.x >> 2;
    const int chunk = blockIdx.x & 3;
    const int t     = threadIdx.x;

    const int s = src[row], d = dst[row];
    for (int i = t; i < NUM_BINS; i += 256) {
        scdf[i] = cdf[s * NUM_BINS + i];
        dcdf[i] = cdf[d * NUM_BINS + i];
    }
    __syncthreads();

    const size_t base = (size_t)row * K_ELEMS + (size_t)chunk * CHUNK;
    const float4* r4  = (const float4*)(residuals + base);
    const float4* w4  = (const float4*)(weights   + base);
    float4*       os4 = (float4*)(out_src + base);
    float4*       od4 = (float4*)(out_dst + base);

    for (int i = t; i < CHUNK / 4; i += 256) {
        float4 r = r4[i], w = w4[i];
        float4 osv, odv;

        {   int b = (int)floorf(r.x * 512.0f + 0.5f);
            bool valid = (b >= 0) & (b < NUM_BINS) & (w.x > 0.0f);
            int bc = min(max(b, 0), NUM_BINS - 1);
            osv.x = valid ? scdf[bc] : 2.0f;
            odv.x = valid ? dcdf[bc] : 2.0f; }
        {   int b = (int)floorf(r.y * 512.0f + 0.5f);
            bool valid = (b >= 0) & (b < NUM_BINS) & (w.y > 0.0f);
            int bc = min(max(b, 0), NUM_BINS - 1);
            osv.y = valid ? scdf[bc] : 2.0f;
            odv.y = valid ? dcdf[bc] : 2.0f; }
        {   int b = (int)floorf(r.z * 512.0f + 0.5f);
            bool valid = (b >= 0) & (b < NUM_BINS) & (w.z > 0.0f);
            int bc = min(max(b, 0), NUM_BINS - 1);
            osv.z = valid ? scdf[bc] : 2.0f;
            odv.z = valid ? dcdf[bc] : 2.0f; }
        {   int b = (int)floorf(r.w * 512.0f + 0.5f);
            bool valid = (b >= 0) & (b < NUM_BINS) & (w.w > 0.0f);
            int bc = min(max(b, 0), NUM_BINS - 1);
            osv.w = valid ? scdf[bc] : 2.0f;
            odv.w = valid ? dcdf[bc] : 2.0f; }

        os4[i] = osv;
        od4[i] = odv;
    }
}

// ---------------------------------------------------------------------------
extern "C" void kernel_launch(void* const* d_in, const int* in_sizes, int n_in,
                              void* d_out, int out_size, void* d_ws, size_t ws_size,
                              hipStream_t stream)
{
    const float* residuals = (const float*)d_in[0];
    const float* weights   = (const float*)d_in[1];
    const int*   src       = (const int*)d_in[2];
    const int*   dst       = (const int*)d_in[3];

    float* out_src = (float*)d_out;
    float* out_dst = out_src + (size_t)N_PAIRS * K_ELEMS;

    float* hist = (float*)d_ws;                    // 128*512 floats
    float* tw   = hist + NUM_NODES * NUM_BINS;     // 128 floats

    const int ws_elems = NUM_NODES * NUM_BINS + NUM_NODES;
    zero_ws_kernel<<<(ws_elems + 255) / 256, 256, 0, stream>>>((float*)d_ws, ws_elems);

    hist_kernel<<<N_PAIRS, 64, 0, stream>>>(residuals, weights, src, dst, hist, tw);

    scan_kernel<<<NUM_NODES, NUM_BINS, 0, stream>>>(hist, tw);

    lookup_kernel<<<N_PAIRS * 4, 256, 0, stream>>>(residuals, weights, src, dst,
                                                   hist, out_src, out_dst);
}